// Round 6
// baseline (1247.910 us; speedup 1.0000x reference)
//
#include <hip/hip_runtime.h>
#include <cstddef>
#include <cstdint>

#define DIM 768
#define DINNER 1536
#define DSTATE 16
#define NLAYERS 4
#define SEQ 1024
#define XPROJ_N 1568
#define VOCAB 50257
#define VOCAB_PAD 50432  // 197 * 256
#define NCHUNK 128
#define CHL 8  // SEQ / NCHUNK

typedef float f32x4 __attribute__((ext_vector_type(4)));
typedef __bf16 bf16x8 __attribute__((ext_vector_type(8)));
typedef __bf16 bf16x4 __attribute__((ext_vector_type(4)));

typedef __attribute__((address_space(1))) const unsigned int as1_u32;
typedef __attribute__((address_space(3))) unsigned int as3_u32;

__device__ __forceinline__ void gl_lds16(const void* g, void* l) {
  __builtin_amdgcn_global_load_lds((as1_u32*)g, (as3_u32*)l, 16, 0, 0);
}

__device__ __forceinline__ float siluf_(float x) {
  return x / (1.f + __expf(-x));
}
__device__ __forceinline__ float softplusf_(float x) {
  return (x > 20.f) ? x : log1pf(expf(x));
}

// ---------------- fp32 -> bf16 convert (row-pad with zeros) ----------------
__global__ __launch_bounds__(256) void k_cvt(const float* __restrict__ src,
                                             __bf16* __restrict__ dst,
                                             int n_src, int n_dst) {
  int e = (blockIdx.x * 256 + threadIdx.x) << 2;
  if (e >= n_dst) return;
  f32x4 v = (f32x4){0.f, 0.f, 0.f, 0.f};
  if (e < n_src) v = *(const f32x4*)(src + e);
  bf16x4 h;
  h.x = (__bf16)v.x; h.y = (__bf16)v.y; h.z = (__bf16)v.z; h.w = (__bf16)v.w;
  *(bf16x4*)(dst + e) = h;
}

// ---------------- embedding gather ----------------
__global__ __launch_bounds__(256) void k_embed(const int* __restrict__ tok,
                                               const float* __restrict__ emb,
                                               float* __restrict__ X) {
  int i4 = blockIdx.x * 256 + threadIdx.x;  // over 1024*192 float4s
  int s = i4 / 192;
  int d4 = i4 - s * 192;
  const f32x4* src = (const f32x4*)(emb + (size_t)tok[s] * DIM);
  ((f32x4*)X)[i4] = src[d4];
}

// ---------------- rmsnorm (fp32 in, bf16 out) ----------------
__global__ __launch_bounds__(256) void k_rmsnorm(const float* __restrict__ x,
                                                 const float* __restrict__ w,
                                                 __bf16* __restrict__ o) {
  int s = blockIdx.x;
  const float* xr = x + (size_t)s * DIM;
  __bf16* orow = o + (size_t)s * DIM;
  int t = threadIdx.x;
  float v0 = xr[t], v1 = xr[t + 256], v2 = xr[t + 512];
  float acc = v0 * v0 + v1 * v1 + v2 * v2;
#pragma unroll
  for (int m = 32; m >= 1; m >>= 1) acc += __shfl_down(acc, m, 64);
  __shared__ float sred[4];
  if ((t & 63) == 0) sred[t >> 6] = acc;
  __syncthreads();
  float tot = sred[0] + sred[1] + sred[2] + sred[3];
  float rs = rsqrtf(tot * (1.f / 768.f) + 1e-6f);
  orow[t] = (__bf16)(v0 * rs * w[t]);
  orow[t + 256] = (__bf16)(v1 * rs * w[t + 256]);
  orow[t + 512] = (__bf16)(v2 * rs * w[t + 512]);
}

// ---------------- single-wave LDS-free GEMM: C[M,N] = A[M,K] * W[N,K]^T -------
// One wave per 64x32 tile. A (bf16) and W (fp32) fragments loaded DIRECTLY from
// global (L2/LLC-resident small matrices) -> no LDS, no barriers; compiler
// software-pipelines the 12 independent loads per K-step.
// EPI: 0 = bf16 store, 1 = bias+softplus -> fp32, 2 = fp32 residual atomic +=,
//      3 = fp32 store, 4 = bf16 store + fp32 aux copy of cols >= DINNER
template <int EPI, int KK>
__global__ __launch_bounds__(64) void k_gemm_w1(const __bf16* __restrict__ A, int lda,
                                                const float* __restrict__ Wf, int ldb,
                                                int N,
                                                const float* __restrict__ bias,
                                                float* __restrict__ aux,
                                                void* __restrict__ Cv, int ldc) {
  const int t = threadIdx.x;
  const int lr = t & 15;
  const int kb = t >> 4;
  const int bm = blockIdx.x * 64;
  const int bn = blockIdx.y * 32;
  const int koff = blockIdx.z * KK;

  const __bf16* arow[4];
#pragma unroll
  for (int i = 0; i < 4; ++i)
    arow[i] = A + (size_t)(bm + i * 16 + lr) * lda + koff + (kb << 3);
  const float* brow[2];
#pragma unroll
  for (int j = 0; j < 2; ++j) {
    int rn = bn + j * 16 + lr;
    if (rn > N - 1) rn = N - 1;
    brow[j] = Wf + (size_t)rn * ldb + koff + (kb << 3);
  }

  f32x4 acc[4][2];
#pragma unroll
  for (int i = 0; i < 4; ++i)
#pragma unroll
    for (int j = 0; j < 2; ++j) acc[i][j] = (f32x4){0.f, 0.f, 0.f, 0.f};

  constexpr int nK = KK >> 5;
#pragma unroll 4
  for (int kt = 0; kt < nK; ++kt) {
    const int k0 = kt << 5;
    bf16x8 af[4], bfr[2];
#pragma unroll
    for (int i = 0; i < 4; ++i) af[i] = *(const bf16x8*)(arow[i] + k0);
#pragma unroll
    for (int j = 0; j < 2; ++j) {
      f32x4 lo = *(const f32x4*)(brow[j] + k0);
      f32x4 hi = *(const f32x4*)(brow[j] + k0 + 4);
      bf16x8 b;
      b[0] = (__bf16)lo.x; b[1] = (__bf16)lo.y; b[2] = (__bf16)lo.z; b[3] = (__bf16)lo.w;
      b[4] = (__bf16)hi.x; b[5] = (__bf16)hi.y; b[6] = (__bf16)hi.z; b[7] = (__bf16)hi.w;
      bfr[j] = b;
    }
#pragma unroll
    for (int i = 0; i < 4; ++i)
#pragma unroll
      for (int j = 0; j < 2; ++j)
        acc[i][j] = __builtin_amdgcn_mfma_f32_16x16x32_bf16(af[i], bfr[j], acc[i][j], 0, 0, 0);
  }

#pragma unroll
  for (int j = 0; j < 2; ++j) {
    const int col = bn + j * 16 + lr;
    if (col >= N) continue;
#pragma unroll
    for (int i = 0; i < 4; ++i) {
#pragma unroll
      for (int r = 0; r < 4; ++r) {
        const int row = bm + i * 16 + (kb << 2) + r;
        float v = acc[i][j][r];
        if (EPI == 0) {
          ((__bf16*)Cv)[(size_t)row * ldc + col] = (__bf16)v;
        } else if (EPI == 1) {
          ((float*)Cv)[(size_t)row * ldc + col] = softplusf_(v + bias[col]);
        } else if (EPI == 2) {
          unsafeAtomicAdd((float*)Cv + (size_t)row * ldc + col, v);
        } else if (EPI == 3) {
          ((float*)Cv)[(size_t)row * ldc + col] = v;
        } else {
          ((__bf16*)Cv)[(size_t)row * ldc + col] = (__bf16)v;
          if (col >= DINNER) aux[(size_t)row * 32 + (col - DINNER)] = v;
        }
      }
    }
  }
}

// ---------------- lm_head GEMM: 256x256 tile, 8 waves, bf16 via gl_lds --------
// logits[1024, VOCAB] = XN[1024, 768] * Wlm[VOCAB_PAD, 768]^T, fp32 out.
__global__ __launch_bounds__(512) void k_gemm_lm(const __bf16* __restrict__ A,
                                                 const __bf16* __restrict__ Wb,
                                                 int N, float* __restrict__ C) {
  __shared__ __align__(16) __bf16 As[2][256 * 32];
  __shared__ __align__(16) __bf16 Bs[2][256 * 32];
  const int tid = threadIdx.x;
  const int lane = tid & 63;
  const int wv = tid >> 6;

  // bijective XCD swizzle (nwg % 8 != 0 safe)
  int id = blockIdx.y * gridDim.x + blockIdx.x;
  const int nwg = gridDim.x * gridDim.y;
  const int q = nwg >> 3, r = nwg & 7;
  const int xcd = id & 7, ii = id >> 3;
  id = (xcd < r ? xcd * (q + 1) : r * (q + 1) + (xcd - r) * q) + ii;
  const int bm = (id % 4) * 256;  // gridDim.x == 4 (M tiles)
  const int bn = (id / 4) * 256;

  const int lr = lane & 15;
  const int kb = lane >> 4;
  const int wm = (wv >> 2) * 128;
  const int wn = (wv & 3) * 64;
  const int rdoff = ((kb ^ ((lr >> 1) & 3)) << 3);

  f32x4 acc[8][4];
#pragma unroll
  for (int i = 0; i < 8; ++i)
#pragma unroll
    for (int j = 0; j < 4; ++j) acc[i][j] = (f32x4){0.f, 0.f, 0.f, 0.f};

  // staging: wave wv covers rows wv*16..+16 (and +128), lane -> (row, swz chunk)
  const int srow = wv * 16 + (lane >> 2);
  const int scs = (((lane & 3) ^ ((lane >> 3) & 3)) << 3);
  const __bf16* Ap = A + (size_t)(bm + srow) * DIM + scs;
  const __bf16* Bp = Wb + (size_t)(bn + srow) * DIM + scs;
  const size_t r128 = (size_t)128 * DIM;

  auto stage = [&](int b, int kt) {
    const int k0 = kt << 5;
    gl_lds16(Ap + k0, &As[b][wv * 512]);
    gl_lds16(Ap + k0 + r128, &As[b][4096 + wv * 512]);
    gl_lds16(Bp + k0, &Bs[b][wv * 512]);
    gl_lds16(Bp + k0 + r128, &Bs[b][4096 + wv * 512]);
  };

  stage(0, 0);
  __syncthreads();

  const int nK = DIM >> 5;  // 24
  int cur = 0;
  for (int kt = 0; kt < nK; ++kt) {
    if (kt + 1 < nK) stage(cur ^ 1, kt + 1);
    bf16x8 af[8], bfr[4];
#pragma unroll
    for (int i = 0; i < 8; ++i)
      af[i] = *(const bf16x8*)(&As[cur][(wm + i * 16 + lr) * 32 + rdoff]);
#pragma unroll
    for (int j = 0; j < 4; ++j)
      bfr[j] = *(const bf16x8*)(&Bs[cur][(wn + j * 16 + lr) * 32 + rdoff]);
#pragma unroll
    for (int i = 0; i < 8; ++i)
#pragma unroll
      for (int j = 0; j < 4; ++j)
        acc[i][j] = __builtin_amdgcn_mfma_f32_16x16x32_bf16(af[i], bfr[j], acc[i][j], 0, 0, 0);
    __syncthreads();
    cur ^= 1;
  }

#pragma unroll
  for (int j = 0; j < 4; ++j) {
    const int col = bn + wn + j * 16 + lr;
    if (col >= N) continue;
#pragma unroll
    for (int i = 0; i < 8; ++i) {
#pragma unroll
      for (int r = 0; r < 4; ++r) {
        const int row = bm + wm + i * 16 + (kb << 2) + r;
        C[(size_t)row * N + col] = acc[i][j][r];
      }
    }
  }
}

// ---------------- causal depthwise conv (width 4) + bias + silu ----------------
__global__ __launch_bounds__(256) void k_conv_silu(const __bf16* __restrict__ XZ,
                                                   const float* __restrict__ cw,
                                                   const float* __restrict__ cb,
                                                   __bf16* __restrict__ out) {
  const int d = blockIdx.x * 256 + threadIdx.x;  // grid.x = 6
  const int s = blockIdx.y;
  const float* wp = cw + d * 4;
  float acc = cb[d];
#pragma unroll
  for (int k = 0; k < 4; ++k) {
    const int ss = s - 3 + k;
    if (ss >= 0) acc += (float)XZ[(size_t)ss * (2 * DINNER) + d] * wp[k];
  }
  out[(size_t)s * DINNER + d] = (__bf16)siluf_(acc);
}

// ---------------- chunked selective scan ----------------
// K1: per (channel, chunk) thread, local scan from h=0; store h_end[16] + sum(dt)
__global__ __launch_bounds__(256) void k_scan1(const float* __restrict__ DT,
                                               const __bf16* __restrict__ XCS,
                                               const float* __restrict__ BC,
                                               const float* __restrict__ A_log,
                                               float* __restrict__ Hloc,
                                               float* __restrict__ Ssum) {
  const int d = blockIdx.x * 256 + threadIdx.x;
  const int c = blockIdx.y;
  const int t0 = c * CHL;
  __shared__ float s_b[CHL][16];
  if (threadIdx.x < CHL * 16) {
    int li = threadIdx.x;
    s_b[li >> 4][li & 15] = BC[(size_t)(t0 + (li >> 4)) * 32 + (li & 15)];
  }
  float a[16];
  const f32x4* alp = (const f32x4*)(A_log + (size_t)d * 16);
#pragma unroll
  for (int q = 0; q < 4; ++q) {
    f32x4 v = alp[q];
    a[q * 4 + 0] = -expf(v.x); a[q * 4 + 1] = -expf(v.y);
    a[q * 4 + 2] = -expf(v.z); a[q * 4 + 3] = -expf(v.w);
  }
  float h[16];
#pragma unroll
  for (int n = 0; n < 16; ++n) h[n] = 0.f;
  float ss = 0.f;
  __syncthreads();
#pragma unroll
  for (int tt = 0; tt < CHL; ++tt) {
    const float dtv = DT[(size_t)(t0 + tt) * DINNER + d];
    const float xv = (float)XCS[(size_t)(t0 + tt) * DINNER + d];
    const float u = dtv * xv;
    ss += dtv;
#pragma unroll
    for (int n = 0; n < 16; ++n)
      h[n] = h[n] * __expf(dtv * a[n]) + u * s_b[tt][n];
  }
  float* hp = Hloc + ((size_t)c * DINNER + d) * 16;
#pragma unroll
  for (int q = 0; q < 4; ++q)
    ((f32x4*)hp)[q] = (f32x4){h[q * 4], h[q * 4 + 1], h[q * 4 + 2], h[q * 4 + 3]};
  Ssum[(size_t)c * DINNER + d] = ss;
}

// K2: in-place rescan over chunks: H[c] becomes chunk-ENTRY state
__global__ __launch_bounds__(256) void k_scan2(float* __restrict__ H,
                                               const float* __restrict__ Ssum,
                                               const float* __restrict__ A_log) {
  const int idx = blockIdx.x * 256 + threadIdx.x;  // over DINNER*16
  const int d = idx >> 4;
  const float a = -expf(A_log[idx]);
  float h = 0.f;
#pragma unroll 8
  for (int c = 0; c < NCHUNK; ++c) {
    float* p = H + (size_t)c * (DINNER * DSTATE) + idx;
    const float bl = *p;
    const float sv = Ssum[(size_t)c * DINNER + d];
    *p = h;
    h = h * __expf(a * sv) + bl;
  }
}

// K3: replay each chunk from entry state, y = h.C + D*x, fused silu(z) gate
__global__ __launch_bounds__(256) void k_scan3(const float* __restrict__ DT,
                                               const __bf16* __restrict__ XCS,
                                               const __bf16* __restrict__ XZ,
                                               const float* __restrict__ BC,
                                               const float* __restrict__ A_log,
                                               const float* __restrict__ Dp,
                                               const float* __restrict__ H,
                                               __bf16* __restrict__ Y) {
  const int d = blockIdx.x * 256 + threadIdx.x;
  const int c = blockIdx.y;
  const int t0 = c * CHL;
  __shared__ float s_bc[CHL][32];
  {
    int li = threadIdx.x;  // CHL*32 = 256
    s_bc[li >> 5][li & 31] = BC[(size_t)(t0 + (li >> 5)) * 32 + (li & 31)];
  }
  float a[16], h[16];
  const f32x4* alp = (const f32x4*)(A_log + (size_t)d * 16);
  const f32x4* hp = (const f32x4*)(H + ((size_t)c * DINNER + d) * 16);
#pragma unroll
  for (int q = 0; q < 4; ++q) {
    f32x4 v = alp[q];
    a[q * 4 + 0] = -expf(v.x); a[q * 4 + 1] = -expf(v.y);
    a[q * 4 + 2] = -expf(v.z); a[q * 4 + 3] = -expf(v.w);
    f32x4 hv = hp[q];
    h[q * 4 + 0] = hv.x; h[q * 4 + 1] = hv.y;
    h[q * 4 + 2] = hv.z; h[q * 4 + 3] = hv.w;
  }
  const float Dd = Dp[d];
  __syncthreads();
#pragma unroll
  for (int tt = 0; tt < CHL; ++tt) {
    const float dtv = DT[(size_t)(t0 + tt) * DINNER + d];
    const float xv = (float)XCS[(size_t)(t0 + tt) * DINNER + d];
    const float zv = (float)XZ[(size_t)(t0 + tt) * (2 * DINNER) + DINNER + d];
    const float u = dtv * xv;
    float y = 0.f;
#pragma unroll
    for (int n = 0; n < 16; ++n) {
      h[n] = h[n] * __expf(dtv * a[n]) + u * s_bc[tt][n];
      y += h[n] * s_bc[tt][16 + n];
    }
    Y[(size_t)(t0 + tt) * DINNER + d] = (__bf16)((y + Dd * xv) * siluf_(zv));
  }
}

extern "C" void kernel_launch(void* const* d_in, const int* in_sizes, int n_in,
                              void* d_out, int out_size, void* d_ws, size_t ws_size,
                              hipStream_t stream) {
  const int* tokens = (const int*)d_in[0];
  const float* embedding = (const float*)d_in[1];
  const float* norm_w = (const float*)d_in[2];
  const float* in_proj_w = (const float*)d_in[3];
  const float* conv_w = (const float*)d_in[4];
  const float* conv_b = (const float*)d_in[5];
  const float* x_proj_w = (const float*)d_in[6];
  const float* dt_w = (const float*)d_in[7];
  const float* dt_b = (const float*)d_in[8];
  const float* A_log = (const float*)d_in[9];
  const float* Dp = (const float*)d_in[10];
  const float* out_proj_w = (const float*)d_in[11];
  const float* normf_w = (const float*)d_in[12];
  const float* lm_head_w = (const float*)d_in[13];
  float* logits = (float*)d_out;

  char* ws = (char*)d_ws;
  float* X = (float*)(ws + 0);                   // 1024*768 f32
  __bf16* XN = (__bf16*)(ws + 3145728);          // 1024*768 bf16
  __bf16* XZ = (__bf16*)(ws + 4718592);          // 1024*3072 bf16
  __bf16* XCS = (__bf16*)(ws + 11010048);        // 1024*1536 bf16
  __bf16* XP = (__bf16*)(ws + 14155776);         // 1024*1568 bf16
  float* DT = (float*)(ws + 17367040);           // 1024*1536 f32
  float* BC = (float*)(ws + 23658496);           // 1024*32 f32
  __bf16* Y = (__bf16*)(ws + 23789568);          // 1024*1536 bf16
  float* Hloc = (float*)(ws + 26935296);         // 128*1536*16 f32 (12.6MB)
  float* Ssum = (float*)(ws + 39518208);         // 128*1536 f32
  __bf16* Wlm = (__bf16*)(ws + 40304640);        // 50432*768 bf16 (77.5MB)
  const bool full = ws_size >= 117768192ull;

  k_embed<<<768, 256, 0, stream>>>(tokens, embedding, X);
  if (full) {
    int blocks = (VOCAB_PAD * DIM / 4 + 255) / 256;
    k_cvt<<<blocks, 256, 0, stream>>>(lm_head_w, Wlm, VOCAB * DIM, VOCAB_PAD * DIM);
  }

  for (int l = 0; l < NLAYERS; ++l) {
    const float* Al = A_log + (size_t)l * DINNER * DSTATE;

    k_rmsnorm<<<SEQ, 256, 0, stream>>>(X, norm_w + (size_t)l * DIM, XN);
    k_gemm_w1<0, 768><<<dim3(16, 96), 64, 0, stream>>>(
        XN, DIM, in_proj_w + (size_t)l * 3072 * DIM, DIM, 2 * DINNER,
        nullptr, nullptr, XZ, 2 * DINNER);
    k_conv_silu<<<dim3(6, SEQ), 256, 0, stream>>>(
        XZ, conv_w + (size_t)l * DINNER * 4, conv_b + (size_t)l * DINNER, XCS);
    k_gemm_w1<4, 1536><<<dim3(16, 49), 64, 0, stream>>>(
        XCS, DINNER, x_proj_w + (size_t)l * XPROJ_N * DINNER, DINNER, XPROJ_N,
        nullptr, BC, XP, XPROJ_N);
    k_gemm_w1<1, 1536><<<dim3(16, 48), 64, 0, stream>>>(
        XP, XPROJ_N, dt_w + (size_t)l * DINNER * DINNER, DINNER, DINNER,
        dt_b + (size_t)l * DINNER, nullptr, DT, DINNER);
    k_scan1<<<dim3(6, NCHUNK), 256, 0, stream>>>(DT, XCS, BC, Al, Hloc, Ssum);
    k_scan2<<<96, 256, 0, stream>>>(Hloc, Ssum, Al);
    k_scan3<<<dim3(6, NCHUNK), 256, 0, stream>>>(DT, XCS, XZ, BC, Al,
                                                 Dp + (size_t)l * DINNER, Hloc, Y);
    // split-K x2: each half adds its partial product onto the residual X
    k_gemm_w1<2, 768><<<dim3(16, 24, 2), 64, 0, stream>>>(
        Y, DINNER, out_proj_w + (size_t)l * DIM * DINNER, DINNER, DIM,
        nullptr, nullptr, X, DIM);
  }
  k_rmsnorm<<<SEQ, 256, 0, stream>>>(X, normf_w, XN);
  if (full) {
    k_gemm_lm<<<dim3(4, 197), 512, 0, stream>>>(XN, Wlm, VOCAB, logits);
  } else {
    k_gemm_w1<3, 768><<<dim3(16, 1571), 64, 0, stream>>>(
        XN, DIM, lm_head_w, DIM, VOCAB, nullptr, nullptr, logits, VOCAB);
  }
}

// Round 7
// 990.139 us; speedup vs baseline: 1.2603x; 1.2603x over previous
//
#include <hip/hip_runtime.h>
#include <cstddef>
#include <cstdint>

#define DIM 768
#define DINNER 1536
#define DSTATE 16
#define NLAYERS 4
#define SEQ 1024
#define XPROJ_N 1568
#define VOCAB 50257
#define NCHUNK 128
#define CHL 8  // SEQ / NCHUNK

typedef float f32x4 __attribute__((ext_vector_type(4)));
typedef __bf16 bf16x8 __attribute__((ext_vector_type(8)));
typedef __bf16 bf16x4 __attribute__((ext_vector_type(4)));

typedef __attribute__((address_space(1))) const unsigned int as1_u32;
typedef __attribute__((address_space(3))) unsigned int as3_u32;

__device__ __forceinline__ void gl_lds16(const void* g, void* l) {
  __builtin_amdgcn_global_load_lds((as1_u32*)g, (as3_u32*)l, 16, 0, 0);
}

__device__ __forceinline__ float siluf_(float x) {
  return x / (1.f + __expf(-x));
}
__device__ __forceinline__ float softplusf_(float x) {
  return (x > 20.f) ? x : log1pf(expf(x));
}

// ---------------- embedding gather ----------------
__global__ __launch_bounds__(256) void k_embed(const int* __restrict__ tok,
                                               const float* __restrict__ emb,
                                               float* __restrict__ X) {
  int i4 = blockIdx.x * 256 + threadIdx.x;  // over 1024*192 float4s
  int s = i4 / 192;
  int d4 = i4 - s * 192;
  const f32x4* src = (const f32x4*)(emb + (size_t)tok[s] * DIM);
  ((f32x4*)X)[i4] = src[d4];
}

// ---------------- rmsnorm (fp32 in, bf16 out) ----------------
__global__ __launch_bounds__(256) void k_rmsnorm(const float* __restrict__ x,
                                                 const float* __restrict__ w,
                                                 __bf16* __restrict__ o) {
  int s = blockIdx.x;
  const float* xr = x + (size_t)s * DIM;
  __bf16* orow = o + (size_t)s * DIM;
  int t = threadIdx.x;
  float v0 = xr[t], v1 = xr[t + 256], v2 = xr[t + 512];
  float acc = v0 * v0 + v1 * v1 + v2 * v2;
#pragma unroll
  for (int m = 32; m >= 1; m >>= 1) acc += __shfl_down(acc, m, 64);
  __shared__ float sred[4];
  if ((t & 63) == 0) sred[t >> 6] = acc;
  __syncthreads();
  float tot = sred[0] + sred[1] + sred[2] + sred[3];
  float rs = rsqrtf(tot * (1.f / 768.f) + 1e-6f);
  orow[t] = (__bf16)(v0 * rs * w[t]);
  orow[t + 256] = (__bf16)(v1 * rs * w[t + 256]);
  orow[t + 512] = (__bf16)(v2 * rs * w[t + 512]);
}

// ---------------- bf16 MFMA NT-GEMM: C[M,N] = A[M,K] * W[N,K]^T ----------------
// A: bf16 via global_load_lds (pre-swizzled source, XOR-swizzled ds_read).
// W: fp32, reg-staged + converted to bf16 in flight (double-buffered).
// MFMA operands SWAPPED (mfma(b,a)): output mapping lane&15 -> M row,
// reg -> 4 consecutive N cols => vectorized 16B/8B epilogue stores.
// SWZ: XCD-aware block swizzle. TM: 128 (MI=4) or 64 (MI=2); N-tile 128.
// gridDim.z = split-K; EPI 3 writes partials at Cv + z*zstride; EPI 2 atomics.
// EPI: 0 = bf16 store, 2 = fp32 residual atomic +=, 3 = fp32 store (+zstride),
//      4 = bf16 store + fp32 aux copy of cols >= DINNER
template <int EPI, int SWZ, int TM>
__global__ __launch_bounds__(256) void k_gemm(const __bf16* __restrict__ A, int lda,
                                              const float* __restrict__ Wf, int ldb,
                                              int N, int K,
                                              float* __restrict__ aux,
                                              void* __restrict__ Cv, int ldc,
                                              int zstride) {
  constexpr int MI = TM / 32;
  __shared__ __align__(16) __bf16 As[2][TM * 32];
  __shared__ __align__(16) __bf16 Bs[2][128 * 32];
  const int tid = threadIdx.x;
  int bx = blockIdx.x, by = blockIdx.y;
  if (SWZ) {
    const int gx = gridDim.x;
    const int id = by * gx + bx;
    const int cpx = (gx * gridDim.y) >> 3;  // requires nwg % 8 == 0
    const int id2 = (id & 7) * cpx + (id >> 3);
    bx = id2 % gx;
    by = id2 / gx;
  }
  const int bm = bx * TM;
  const int bn = by * 128;
  const int koff = blockIdx.z * K;
  const int lane = tid & 63;
  const int wv = tid >> 6;
  const int wm = (wv >> 1) * (TM / 2);
  const int wn = (wv & 1) * 64;
  const int lr = lane & 15;
  const int kb = lane >> 4;
  const int rdoff = ((kb ^ ((lr >> 1) & 3)) << 3);  // de-swizzle for ds_read

  f32x4 acc[MI][4];
#pragma unroll
  for (int i = 0; i < MI; ++i)
#pragma unroll
    for (int j = 0; j < 4; ++j) acc[i][j] = (f32x4){0.f, 0.f, 0.f, 0.f};

  // A staging: lane l covers row wv*16+(l>>2), pre-swizzled 16B chunk
  const int srow = wv * 16 + (lane >> 2);
  const int scs = (((lane & 3) ^ ((lane >> 3) & 3)) << 3);
  const __bf16* Ap = A + (size_t)(bm + srow) * lda + koff + scs;
  const size_t a64 = (size_t)64 * lda;

  // B reg staging geometry: thread covers rows r0+32p, 8B granule c4
  const int r0 = tid >> 3;                // 0..31
  const int c4 = (tid & 7) << 2;          // elem offset 0..28
  const int bwr = (((c4 >> 3) ^ ((r0 >> 1) & 3)) << 3) | (c4 & 7);  // swizzled
  const float* Wp = Wf + koff + c4;

  auto stageA = [&](int b, int kt) {
    const int k0 = kt << 5;
    gl_lds16(Ap + k0, &As[b][wv * 512]);
    if (TM == 128) gl_lds16(Ap + k0 + a64, &As[b][wv * 512 + 2048]);
  };
  f32x4 breg[4];
  auto loadB = [&](int kt) {
#pragma unroll
    for (int p = 0; p < 4; ++p) {
      int rn = bn + r0 + (p << 5);
      if (rn > N - 1) rn = N - 1;
      breg[p] = *(const f32x4*)(Wp + (size_t)rn * ldb + (kt << 5));
    }
  };
  auto writeB = [&](int b) {
#pragma unroll
    for (int p = 0; p < 4; ++p) {
      bf16x4 bh;
      bh.x = (__bf16)breg[p].x; bh.y = (__bf16)breg[p].y;
      bh.z = (__bf16)breg[p].z; bh.w = (__bf16)breg[p].w;
      *(bf16x4*)(&Bs[b][(r0 + (p << 5)) * 32 + bwr]) = bh;
    }
  };

  // prologue: tile 0 into buffer 0
  stageA(0, 0);
  loadB(0);
  writeB(0);
  __syncthreads();

  const int nK = K >> 5;
  int cur = 0;
  for (int kt = 0; kt < nK; ++kt) {
    const bool more = (kt + 1 < nK);
    if (more) {
      stageA(cur ^ 1, kt + 1);
      loadB(kt + 1);
    }
    bf16x8 af[MI], bfr[4];
#pragma unroll
    for (int i = 0; i < MI; ++i)
      af[i] = *(const bf16x8*)(&As[cur][(wm + i * 16 + lr) * 32 + rdoff]);
#pragma unroll
    for (int j = 0; j < 4; ++j)
      bfr[j] = *(const bf16x8*)(&Bs[cur][(wn + j * 16 + lr) * 32 + rdoff]);
#pragma unroll
    for (int i = 0; i < MI; ++i)
#pragma unroll
      for (int j = 0; j < 4; ++j)
        acc[i][j] = __builtin_amdgcn_mfma_f32_16x16x32_bf16(bfr[j], af[i], acc[i][j], 0, 0, 0);
    if (more) writeB(cur ^ 1);
    __syncthreads();
    cur ^= 1;
  }

  // epilogue: row = ...+lr, col = ...+(kb<<2)+r (4 consecutive) -> vector stores
#pragma unroll
  for (int i = 0; i < MI; ++i) {
    const int row = bm + wm + i * 16 + lr;
#pragma unroll
    for (int j = 0; j < 4; ++j) {
      const int col = bn + wn + j * 16 + (kb << 2);
      f32x4 v = acc[i][j];
      if (EPI == 0) {
        if (col < N) {
          bf16x4 h;
          h.x = (__bf16)v.x; h.y = (__bf16)v.y; h.z = (__bf16)v.z; h.w = (__bf16)v.w;
          *(bf16x4*)((__bf16*)Cv + (size_t)row * ldc + col) = h;
        }
      } else if (EPI == 2) {
        if (col < N) {
          float* cp = (float*)Cv + (size_t)row * ldc + col;
          unsafeAtomicAdd(cp + 0, v.x);
          unsafeAtomicAdd(cp + 1, v.y);
          unsafeAtomicAdd(cp + 2, v.z);
          unsafeAtomicAdd(cp + 3, v.w);
        }
      } else if (EPI == 3) {
        float* cp = (float*)Cv + (size_t)blockIdx.z * zstride +
                    (size_t)row * ldc + col;
        if (col + 3 < N) {
          *(f32x4*)cp = v;
        } else {
#pragma unroll
          for (int r = 0; r < 4; ++r)
            if (col + r < N) cp[r] = v[r];
        }
      } else {  // EPI == 4
        if (col < N) {
          bf16x4 h;
          h.x = (__bf16)v.x; h.y = (__bf16)v.y; h.z = (__bf16)v.z; h.w = (__bf16)v.w;
          *(bf16x4*)((__bf16*)Cv + (size_t)row * ldc + col) = h;
          if (col >= DINNER)
            *(f32x4*)(aux + (size_t)row * 32 + (col - DINNER)) = v;
        }
      }
    }
  }
}

// ---------------- causal depthwise conv (width 4) + bias + silu ----------------
__global__ __launch_bounds__(256) void k_conv_silu(const __bf16* __restrict__ XZ,
                                                   const float* __restrict__ cw,
                                                   const float* __restrict__ cb,
                                                   __bf16* __restrict__ out) {
  const int d = blockIdx.x * 256 + threadIdx.x;  // grid.x = 6
  const int s = blockIdx.y;
  const float* wp = cw + d * 4;
  float acc = cb[d];
#pragma unroll
  for (int k = 0; k < 4; ++k) {
    const int ss = s - 3 + k;
    if (ss >= 0) acc += (float)XZ[(size_t)ss * (2 * DINNER) + d] * wp[k];
  }
  out[(size_t)s * DINNER + d] = (__bf16)siluf_(acc);
}

// ---------------- chunked selective scan ----------------
// dt = softplus(DT[idx] + DT[idx + SEQ*DINNER] + dt_b[d])  (split-K partials)
// K1: per (channel, chunk) thread, local scan from h=0; store h_end[16] + sum(dt)
__global__ __launch_bounds__(256) void k_scan1(const float* __restrict__ DT,
                                               const float* __restrict__ dt_b,
                                               const __bf16* __restrict__ XCS,
                                               const float* __restrict__ BC,
                                               const float* __restrict__ A_log,
                                               float* __restrict__ Hloc,
                                               float* __restrict__ Ssum) {
  const int d = blockIdx.x * 256 + threadIdx.x;
  const int c = blockIdx.y;
  const int t0 = c * CHL;
  __shared__ float s_b[CHL][16];
  if (threadIdx.x < CHL * 16) {
    int li = threadIdx.x;
    s_b[li >> 4][li & 15] = BC[(size_t)(t0 + (li >> 4)) * 32 + (li & 15)];
  }
  float a[16];
  const f32x4* alp = (const f32x4*)(A_log + (size_t)d * 16);
#pragma unroll
  for (int q = 0; q < 4; ++q) {
    f32x4 v = alp[q];
    a[q * 4 + 0] = -expf(v.x); a[q * 4 + 1] = -expf(v.y);
    a[q * 4 + 2] = -expf(v.z); a[q * 4 + 3] = -expf(v.w);
  }
  const float bias = dt_b[d];
  float h[16];
#pragma unroll
  for (int n = 0; n < 16; ++n) h[n] = 0.f;
  float ss = 0.f;
  __syncthreads();
#pragma unroll
  for (int tt = 0; tt < CHL; ++tt) {
    const size_t idx = (size_t)(t0 + tt) * DINNER + d;
    const float dtv = softplusf_(DT[idx] + DT[idx + (size_t)SEQ * DINNER] + bias);
    const float xv = (float)XCS[idx];
    const float u = dtv * xv;
    ss += dtv;
#pragma unroll
    for (int n = 0; n < 16; ++n)
      h[n] = h[n] * __expf(dtv * a[n]) + u * s_b[tt][n];
  }
  float* hp = Hloc + ((size_t)c * DINNER + d) * 16;
#pragma unroll
  for (int q = 0; q < 4; ++q)
    ((f32x4*)hp)[q] = (f32x4){h[q * 4], h[q * 4 + 1], h[q * 4 + 2], h[q * 4 + 3]};
  Ssum[(size_t)c * DINNER + d] = ss;
}

// K2: in-place rescan over chunks: H[c] becomes chunk-ENTRY state
__global__ __launch_bounds__(256) void k_scan2(float* __restrict__ H,
                                               const float* __restrict__ Ssum,
                                               const float* __restrict__ A_log) {
  const int idx = blockIdx.x * 256 + threadIdx.x;  // over DINNER*16
  const int d = idx >> 4;
  const float a = -expf(A_log[idx]);
  float h = 0.f;
#pragma unroll 8
  for (int c = 0; c < NCHUNK; ++c) {
    float* p = H + (size_t)c * (DINNER * DSTATE) + idx;
    const float bl = *p;
    const float sv = Ssum[(size_t)c * DINNER + d];
    *p = h;
    h = h * __expf(a * sv) + bl;
  }
}

// K3: replay each chunk from entry state, y = h.C + D*x, fused silu(z) gate
__global__ __launch_bounds__(256) void k_scan3(const float* __restrict__ DT,
                                               const float* __restrict__ dt_b,
                                               const __bf16* __restrict__ XCS,
                                               const __bf16* __restrict__ XZ,
                                               const float* __restrict__ BC,
                                               const float* __restrict__ A_log,
                                               const float* __restrict__ Dp,
                                               const float* __restrict__ H,
                                               __bf16* __restrict__ Y) {
  const int d = blockIdx.x * 256 + threadIdx.x;
  const int c = blockIdx.y;
  const int t0 = c * CHL;
  __shared__ float s_bc[CHL][32];
  {
    int li = threadIdx.x;  // CHL*32 = 256
    s_bc[li >> 5][li & 31] = BC[(size_t)(t0 + (li >> 5)) * 32 + (li & 31)];
  }
  float a[16], h[16];
  const f32x4* alp = (const f32x4*)(A_log + (size_t)d * 16);
  const f32x4* hp = (const f32x4*)(H + ((size_t)c * DINNER + d) * 16);
#pragma unroll
  for (int q = 0; q < 4; ++q) {
    f32x4 v = alp[q];
    a[q * 4 + 0] = -expf(v.x); a[q * 4 + 1] = -expf(v.y);
    a[q * 4 + 2] = -expf(v.z); a[q * 4 + 3] = -expf(v.w);
    f32x4 hv = hp[q];
    h[q * 4 + 0] = hv.x; h[q * 4 + 1] = hv.y;
    h[q * 4 + 2] = hv.z; h[q * 4 + 3] = hv.w;
  }
  const float Dd = Dp[d];
  const float bias = dt_b[d];
  __syncthreads();
#pragma unroll
  for (int tt = 0; tt < CHL; ++tt) {
    const size_t idx = (size_t)(t0 + tt) * DINNER + d;
    const float dtv = softplusf_(DT[idx] + DT[idx + (size_t)SEQ * DINNER] + bias);
    const float xv = (float)XCS[idx];
    const float zv = (float)XZ[(size_t)(t0 + tt) * (2 * DINNER) + DINNER + d];
    const float u = dtv * xv;
    float y = 0.f;
#pragma unroll
    for (int n = 0; n < 16; ++n) {
      h[n] = h[n] * __expf(dtv * a[n]) + u * s_bc[tt][n];
      y += h[n] * s_bc[tt][16 + n];
    }
    Y[idx] = (__bf16)((y + Dd * xv) * siluf_(zv));
  }
}

extern "C" void kernel_launch(void* const* d_in, const int* in_sizes, int n_in,
                              void* d_out, int out_size, void* d_ws, size_t ws_size,
                              hipStream_t stream) {
  const int* tokens = (const int*)d_in[0];
  const float* embedding = (const float*)d_in[1];
  const float* norm_w = (const float*)d_in[2];
  const float* in_proj_w = (const float*)d_in[3];
  const float* conv_w = (const float*)d_in[4];
  const float* conv_b = (const float*)d_in[5];
  const float* x_proj_w = (const float*)d_in[6];
  const float* dt_w = (const float*)d_in[7];
  const float* dt_b = (const float*)d_in[8];
  const float* A_log = (const float*)d_in[9];
  const float* Dp = (const float*)d_in[10];
  const float* out_proj_w = (const float*)d_in[11];
  const float* normf_w = (const float*)d_in[12];
  const float* lm_head_w = (const float*)d_in[13];
  float* logits = (float*)d_out;

  char* ws = (char*)d_ws;
  float* X = (float*)(ws + 0);                   // 1024*768 f32
  __bf16* XN = (__bf16*)(ws + 3145728);          // 1024*768 bf16
  __bf16* XZ = (__bf16*)(ws + 4718592);          // 1024*3072 bf16
  __bf16* XCS = (__bf16*)(ws + 11010048);        // 1024*1536 bf16
  __bf16* XP = (__bf16*)(ws + 14155776);         // 1024*1568 bf16
  float* DT = (float*)(ws + 17367040);           // 2 x 1024*1536 f32 (split-K)
  float* BC = (float*)(ws + 29949952);           // 1024*32 f32
  __bf16* Y = (__bf16*)(ws + 30081024);          // 1024*1536 bf16
  float* Hloc = (float*)(ws + 33226752);         // 128*1536*16 f32 (12.6MB)
  float* Ssum = (float*)(ws + 45809664);         // 128*1536 f32

  k_embed<<<768, 256, 0, stream>>>(tokens, embedding, X);

  for (int l = 0; l < NLAYERS; ++l) {
    const float* Al = A_log + (size_t)l * DINNER * DSTATE;
    const float* bl = dt_b + (size_t)l * DINNER;

    k_rmsnorm<<<SEQ, 256, 0, stream>>>(X, norm_w + (size_t)l * DIM, XN);
    k_gemm<0, 0, 64><<<dim3(16, 24), 256, 0, stream>>>(
        XN, DIM, in_proj_w + (size_t)l * 3072 * DIM, DIM, 2 * DINNER, DIM,
        nullptr, XZ, 2 * DINNER, 0);
    k_conv_silu<<<dim3(6, SEQ), 256, 0, stream>>>(
        XZ, conv_w + (size_t)l * DINNER * 4, conv_b + (size_t)l * DINNER, XCS);
    k_gemm<4, 0, 64><<<dim3(16, 13), 256, 0, stream>>>(
        XCS, DINNER, x_proj_w + (size_t)l * XPROJ_N * DINNER, DINNER, XPROJ_N,
        DINNER, BC, XP, XPROJ_N, 0);
    // dt GEMM split-K x2 into two fp32 partial buffers (softplus+bias in scans)
    k_gemm<3, 0, 64><<<dim3(16, 12, 2), 256, 0, stream>>>(
        XP, XPROJ_N, dt_w + (size_t)l * DINNER * DINNER, DINNER, DINNER,
        DINNER / 2, nullptr, DT, DINNER, SEQ * DINNER);
    k_scan1<<<dim3(6, NCHUNK), 256, 0, stream>>>(DT, bl, XCS, BC, Al, Hloc, Ssum);
    k_scan2<<<96, 256, 0, stream>>>(Hloc, Ssum, Al);
    k_scan3<<<dim3(6, NCHUNK), 256, 0, stream>>>(DT, bl, XCS, XZ, BC, Al,
                                                 Dp + (size_t)l * DINNER, Hloc, Y);
    // split-K x2: each half adds its partial product onto the residual X
    k_gemm<2, 0, 64><<<dim3(16, 6, 2), 256, 0, stream>>>(
        Y, DINNER, out_proj_w + (size_t)l * DIM * DINNER, DINNER, DIM,
        DINNER / 2, nullptr, X, DIM, 0);
  }
  k_rmsnorm<<<SEQ, 256, 0, stream>>>(X, normf_w, XN);
  k_gemm<3, 1, 128><<<dim3(8, 393), 256, 0, stream>>>(
      XN, DIM, lm_head_w, DIM, VOCAB, DIM, nullptr, logits, VOCAB, 0);
}